// Round 5
// baseline (54.395 us; speedup 1.0000x reference)
//
#include <hip/hip_runtime.h>

// Problem constants (match reference setup_inputs)
#define BATCH 2
#define NPART 4096
#define TI 256                  // threads per block
#define IPT 4                   // i-particles per thread (amortizes j-reads)
#define ITILE (TI * IPT)        // 1024 i per block
#define NITILES (NPART / ITILE) // 4
#define JSEGS 128               // -> 128*4*2 = 1024 blocks (4/CU, 4 waves/SIMD)
#define SEG (NPART / JSEGS)     // 32 j-particles staged in LDS per block

typedef float v2f __attribute__((ext_vector_type(2)));

// Inner loop: IPT i's per thread x 2 j's per iteration (packed f32).
// One v_rcp per (i, j-pair): inv(a),inv(b) = rcp(a*b)*{b,a}.
// MASKED=true only for blocks whose j-range overlaps their i-range.
template <bool MASKED>
__device__ inline void lj_inner(const v2f* __restrict__ xs, const v2f* __restrict__ ys,
                                const v2f* __restrict__ zs,
                                const float* qx, const float* qy, const float* qz,
                                v2f* fx, v2f* fy, v2f* fz) {
    #pragma unroll 2
    for (int jj = 0; jj < SEG / 2; ++jj) {
        const v2f jx = xs[jj];   // one broadcast j-load feeds IPT*2 = 8 pairs
        const v2f jy = ys[jj];
        const v2f jz = zs[jj];
        #pragma unroll
        for (int k = 0; k < IPT; ++k) {
            const v2f dx = (v2f)qx[k] - jx;
            const v2f dy = (v2f)qy[k] - jy;
            const v2f dz = (v2f)qz[k] - jz;
            v2f r2 = dx * dx;
            r2 = __builtin_elementwise_fma(dy, dy, r2);
            r2 = __builtin_elementwise_fma(dz, dz, r2);

            v2f r2s = r2;
            if (MASKED) {   // r2==0.0f exactly <=> i==j (reference's mask)
                r2s.x = (r2.x > 0.0f) ? r2.x : 1.0f;
                r2s.y = (r2.y > 0.0f) ? r2.y : 1.0f;
            }
            // combined reciprocal: 1 transcendental per 2 pairs
            const float rc = __builtin_amdgcn_rcpf(r2s.x * r2s.y);
            v2f inv;
            inv.x = rc * r2s.y;
            inv.y = rc * r2s.x;
            if (MASKED) {
                inv.x = (r2.x > 0.0f) ? inv.x : 0.0f;
                inv.y = (r2.y > 0.0f) ? inv.y : 0.0f;
            }
            const v2f inv2 = inv * inv;
            const v2f s6 = inv2 * inv;                                   // sigma = 1
            const v2f c1 = __builtin_elementwise_fma((v2f)48.0f, s6, (v2f)(-24.0f));
            const v2f coeff = (inv * s6) * c1;    // 24*inv*s6*(2*s6-1)
            fx[k] = __builtin_elementwise_fma(coeff, dx, fx[k]);
            fy[k] = __builtin_elementwise_fma(coeff, dy, fy[k]);
            fz[k] = __builtin_elementwise_fma(coeff, dz, fz[k]);
        }
    }
}

// Grid: (JSEGS, NITILES, BATCH), block TI=256. Partials via atomicAdd.
// jseg==0 blocks also emit dq = p/m for their i-range.
__global__ __launch_bounds__(256) void lj_kernel(const float* __restrict__ q,
                                                 const float* __restrict__ p,
                                                 const float* __restrict__ m,
                                                 float* __restrict__ dq,
                                                 float* __restrict__ dp) {
    __shared__ float qsx[SEG], qsy[SEG], qsz[SEG];

    const int jseg  = blockIdx.x;
    const int itile = blockIdx.y;
    const int b     = blockIdx.z;

    const float* qb = q + (size_t)b * NPART * 3;

    if (threadIdx.x < SEG) {
        const int k = threadIdx.x;
        const int jb = (jseg * SEG + k) * 3;
        qsx[k] = qb[jb + 0];
        qsy[k] = qb[jb + 1];
        qsz[k] = qb[jb + 2];
    }
    __syncthreads();

    const int i0 = itile * ITILE + threadIdx.x;
    float qx[IPT], qy[IPT], qz[IPT];
    #pragma unroll
    for (int k = 0; k < IPT; ++k) {
        const int i = i0 + k * TI;
        qx[k] = qb[i * 3 + 0];
        qy[k] = qb[i * 3 + 1];
        qz[k] = qb[i * 3 + 2];
    }

    v2f fx[IPT], fy[IPT], fz[IPT];
    #pragma unroll
    for (int k = 0; k < IPT; ++k) { fx[k] = (v2f)0.0f; fy[k] = (v2f)0.0f; fz[k] = (v2f)0.0f; }

    // Diagonal possible iff j-range within this block's i-range (ITILE/SEG = 32)
    if ((jseg >> 5) == itile) {
        lj_inner<true >((const v2f*)qsx, (const v2f*)qsy, (const v2f*)qsz,
                        qx, qy, qz, fx, fy, fz);
    } else {
        lj_inner<false>((const v2f*)qsx, (const v2f*)qsy, (const v2f*)qsz,
                        qx, qy, qz, fx, fy, fz);
    }

    #pragma unroll
    for (int k = 0; k < IPT; ++k) {
        const int i = i0 + k * TI;
        float* out = &dp[((size_t)b * NPART + i) * 3];
        atomicAdd(&out[0], fx[k].x + fx[k].y);
        atomicAdd(&out[1], fy[k].x + fy[k].y);
        atomicAdd(&out[2], fz[k].x + fz[k].y);
    }

    // dq = p/m, emitted exactly once per (b,i) by the jseg==0 blocks
    if (jseg == 0) {
        #pragma unroll
        for (int k = 0; k < IPT; ++k) {
            const int i = i0 + k * TI;
            const size_t base = ((size_t)b * NPART + i) * 3;
            const float invm = 1.0f / m[(size_t)b * NPART + i];  // exact IEEE div
            dq[base + 0] = p[base + 0] * invm;
            dq[base + 1] = p[base + 1] * invm;
            dq[base + 2] = p[base + 2] * invm;
        }
    }
}

extern "C" void kernel_launch(void* const* d_in, const int* in_sizes, int n_in,
                              void* d_out, int out_size, void* d_ws, size_t ws_size,
                              hipStream_t stream) {
    const float* q = (const float*)d_in[0];
    const float* p = (const float*)d_in[1];
    const float* m = (const float*)d_in[2];
    // d_in[3] = t, unused by the reference outputs

    const int n_elem = BATCH * NPART * 3;   // 24576 per output tensor
    float* dq_out = (float*)d_out;          // first output: dq
    float* dp_out = (float*)d_out + n_elem; // second output: dp

    // dp is accumulated atomically -> must start from zero every call
    hipMemsetAsync(dp_out, 0, (size_t)n_elem * sizeof(float), stream);

    dim3 grid(JSEGS, NITILES, BATCH);
    lj_kernel<<<grid, TI, 0, stream>>>(q, p, m, dq_out, dp_out);
}

// Round 6
// 23.106 us; speedup vs baseline: 2.3541x; 2.3541x over previous
//
#include <hip/hip_runtime.h>

// Problem constants (match reference setup_inputs)
#define BATCH 2
#define NPART 4096
#define TI 256                  // threads per block
#define IPT 2                   // i-particles per thread (amortizes j-broadcasts)
#define ITILE (TI * IPT)        // 512 i per block
#define NITILES (NPART / ITILE) // 8
#define JSEGS 32                // -> 32*8*2 = 512 blocks (2/CU)
#define SEG (NPART / JSEGS)     // 128 j-particles staged in LDS per block
#define PLANE (BATCH * NPART)   // 8192 floats per (jseg,c) partial plane

typedef float v2f __attribute__((ext_vector_type(2)));

// Inner loop: IPT i's per thread x 2 j's per iteration (packed f32).
// One v_rcp per (i, j-pair): inv(a),inv(b) = rcp(a*b)*{b,a}.
// MASKED=true only for blocks whose j-range overlaps their i-range.
template <bool MASKED>
__device__ inline void lj_inner(const v2f* __restrict__ xs, const v2f* __restrict__ ys,
                                const v2f* __restrict__ zs,
                                const float* qx, const float* qy, const float* qz,
                                v2f* fx, v2f* fy, v2f* fz) {
    #pragma unroll 4
    for (int jj = 0; jj < SEG / 2; ++jj) {
        const v2f jx = xs[jj];   // one broadcast j-load feeds IPT*2 = 4 pairs
        const v2f jy = ys[jj];
        const v2f jz = zs[jj];
        #pragma unroll
        for (int k = 0; k < IPT; ++k) {
            const v2f dx = (v2f)qx[k] - jx;
            const v2f dy = (v2f)qy[k] - jy;
            const v2f dz = (v2f)qz[k] - jz;
            v2f r2 = dx * dx;
            r2 = __builtin_elementwise_fma(dy, dy, r2);
            r2 = __builtin_elementwise_fma(dz, dz, r2);

            v2f r2s = r2;
            if (MASKED) {   // r2==0.0f exactly <=> i==j (reference's mask)
                r2s.x = (r2.x > 0.0f) ? r2.x : 1.0f;
                r2s.y = (r2.y > 0.0f) ? r2.y : 1.0f;
            }
            // combined reciprocal: 1 transcendental per 2 pairs
            const float rc = __builtin_amdgcn_rcpf(r2s.x * r2s.y);
            v2f inv;
            inv.x = rc * r2s.y;
            inv.y = rc * r2s.x;
            if (MASKED) {
                inv.x = (r2.x > 0.0f) ? inv.x : 0.0f;
                inv.y = (r2.y > 0.0f) ? inv.y : 0.0f;
            }
            const v2f inv2 = inv * inv;
            const v2f s6 = inv2 * inv;                                   // sigma = 1
            const v2f c1 = __builtin_elementwise_fma((v2f)48.0f, s6, (v2f)(-24.0f));
            const v2f coeff = (inv * s6) * c1;    // 24*inv*s6*(2*s6-1)
            fx[k] = __builtin_elementwise_fma(coeff, dx, fx[k]);
            fy[k] = __builtin_elementwise_fma(coeff, dy, fy[k]);
            fz[k] = __builtin_elementwise_fma(coeff, dz, fz[k]);
        }
    }
}

// Grid: (JSEGS, NITILES, BATCH), block TI=256.
// Plain coalesced stores of per-jseg partials (no atomics, no memset):
//   ws[(jseg*3 + c) * PLANE + b*NPART + i]
__global__ __launch_bounds__(256) void lj_kernel(const float* __restrict__ q,
                                                 float* __restrict__ ws) {
    __shared__ float qsx[SEG], qsy[SEG], qsz[SEG];

    const int jseg  = blockIdx.x;
    const int itile = blockIdx.y;
    const int b     = blockIdx.z;

    const float* qb = q + (size_t)b * NPART * 3;

    if (threadIdx.x < SEG) {
        const int k = threadIdx.x;
        const int jb = (jseg * SEG + k) * 3;
        qsx[k] = qb[jb + 0];
        qsy[k] = qb[jb + 1];
        qsz[k] = qb[jb + 2];
    }
    __syncthreads();

    const int i0 = itile * ITILE + threadIdx.x;
    float qx[IPT], qy[IPT], qz[IPT];
    #pragma unroll
    for (int k = 0; k < IPT; ++k) {
        const int i = i0 + k * TI;
        qx[k] = qb[i * 3 + 0];
        qy[k] = qb[i * 3 + 1];
        qz[k] = qb[i * 3 + 2];
    }

    v2f fx[IPT], fy[IPT], fz[IPT];
    #pragma unroll
    for (int k = 0; k < IPT; ++k) { fx[k] = (v2f)0.0f; fy[k] = (v2f)0.0f; fz[k] = (v2f)0.0f; }

    // Diagonal possible iff j-range within this block's i-range (ITILE/SEG = 4)
    if ((jseg >> 2) == itile) {
        lj_inner<true >((const v2f*)qsx, (const v2f*)qsy, (const v2f*)qsz,
                        qx, qy, qz, fx, fy, fz);
    } else {
        lj_inner<false>((const v2f*)qsx, (const v2f*)qsy, (const v2f*)qsz,
                        qx, qy, qz, fx, fy, fz);
    }

    const size_t wbase = (size_t)(jseg * 3) * PLANE + (size_t)b * NPART;
    #pragma unroll
    for (int k = 0; k < IPT; ++k) {
        const int i = i0 + k * TI;
        ws[wbase + i]             = fx[k].x + fx[k].y;
        ws[wbase + PLANE + i]     = fy[k].x + fy[k].y;
        ws[wbase + 2 * PLANE + i] = fz[k].x + fz[k].y;
    }
}

// Sum 32 per-jseg partials per dp element (L2-resident, coalesced);
// fuse dq = p/m. o in [0, 24576) maps to (c, b*NPART+i).
__global__ __launch_bounds__(256) void reduce_kernel(const float* __restrict__ ws,
                                                     const float* __restrict__ p,
                                                     const float* __restrict__ m,
                                                     float* __restrict__ dq,
                                                     float* __restrict__ dp) {
    const int o  = blockIdx.x * 256 + threadIdx.x;   // 24576 threads, 96 blocks
    const int c  = o >> 13;          // / PLANE
    const int bi = o & (PLANE - 1);  // b*NPART + i

    float s0 = 0.0f, s1 = 0.0f, s2 = 0.0f, s3 = 0.0f;
    #pragma unroll
    for (int js = 0; js < JSEGS; js += 4) {
        s0 += ws[(size_t)((js + 0) * 3 + c) * PLANE + bi];
        s1 += ws[(size_t)((js + 1) * 3 + c) * PLANE + bi];
        s2 += ws[(size_t)((js + 2) * 3 + c) * PLANE + bi];
        s3 += ws[(size_t)((js + 3) * 3 + c) * PLANE + bi];
    }
    dp[(size_t)bi * 3 + c] = (s0 + s1) + (s2 + s3);

    // dq = p/m for flat element o (exact IEEE div, only 24576 of them)
    dq[o] = p[o] / m[o / 3];
}

extern "C" void kernel_launch(void* const* d_in, const int* in_sizes, int n_in,
                              void* d_out, int out_size, void* d_ws, size_t ws_size,
                              hipStream_t stream) {
    const float* q = (const float*)d_in[0];
    const float* p = (const float*)d_in[1];
    const float* m = (const float*)d_in[2];
    // d_in[3] = t, unused by the reference outputs

    const int n_elem = BATCH * NPART * 3;   // 24576 per output tensor
    float* dq_out = (float*)d_out;          // first output: dq
    float* dp_out = (float*)d_out + n_elem; // second output: dp
    float* ws     = (float*)d_ws;           // 32*3*8192 floats = 3 MB partials

    dim3 grid(JSEGS, NITILES, BATCH);
    lj_kernel<<<grid, TI, 0, stream>>>(q, ws);

    reduce_kernel<<<n_elem / 256, 256, 0, stream>>>(ws, p, m, dq_out, dp_out);
}

// Round 7
// 22.209 us; speedup vs baseline: 2.4492x; 1.0404x over previous
//
#include <hip/hip_runtime.h>

// Problem constants (match reference setup_inputs)
#define BATCH 2
#define NPART 4096
#define TI 256                  // threads per block
#define IPT 2                   // i-particles per thread (amortizes j-broadcasts)
#define ITILE (TI * IPT)        // 512 i per block
#define NITILES (NPART / ITILE) // 8
#define JSEGS 64                // -> 64*8*2 = 1024 blocks (4/CU, 4 waves/SIMD)
#define SEG (NPART / JSEGS)     // 64 j-particles staged in LDS per block
#define PLANE (BATCH * NPART)   // 8192 floats per (jseg,c) partial plane

typedef float v2f __attribute__((ext_vector_type(2)));

// Inner loop: IPT i's per thread x 2 j's per iteration (packed f32 -> v_pk_*).
// Per-element v_rcp keeps the dependency chain short (r2 -> rcp -> s6 -> coeff).
// MASKED=true only for blocks whose j-range overlaps their i-range.
template <bool MASKED>
__device__ inline void lj_inner(const v2f* __restrict__ xs, const v2f* __restrict__ ys,
                                const v2f* __restrict__ zs,
                                const float* qx, const float* qy, const float* qz,
                                v2f* fx, v2f* fy, v2f* fz) {
    #pragma unroll 4
    for (int jj = 0; jj < SEG / 2; ++jj) {
        const v2f jx = xs[jj];   // one broadcast j-load feeds IPT*2 = 4 pairs
        const v2f jy = ys[jj];
        const v2f jz = zs[jj];
        #pragma unroll
        for (int k = 0; k < IPT; ++k) {
            const v2f dx = (v2f)qx[k] - jx;
            const v2f dy = (v2f)qy[k] - jy;
            const v2f dz = (v2f)qz[k] - jz;
            v2f r2 = dx * dx;
            r2 = __builtin_elementwise_fma(dy, dy, r2);
            r2 = __builtin_elementwise_fma(dz, dz, r2);

            // per-element approximate reciprocal; r2==0.0f exactly <=> i==j
            v2f inv;
            inv.x = __builtin_amdgcn_rcpf(r2.x);
            inv.y = __builtin_amdgcn_rcpf(r2.y);
            if (MASKED) {
                inv.x = (r2.x > 0.0f) ? inv.x : 0.0f;
                inv.y = (r2.y > 0.0f) ? inv.y : 0.0f;
            }
            const v2f inv2 = inv * inv;
            const v2f s6 = inv2 * inv;                                   // sigma = 1
            const v2f c1 = __builtin_elementwise_fma((v2f)48.0f, s6, (v2f)(-24.0f));
            const v2f coeff = (inv * s6) * c1;    // 24*inv*s6*(2*s6-1)
            fx[k] = __builtin_elementwise_fma(coeff, dx, fx[k]);
            fy[k] = __builtin_elementwise_fma(coeff, dy, fy[k]);
            fz[k] = __builtin_elementwise_fma(coeff, dz, fz[k]);
        }
    }
}

// Grid: (JSEGS, NITILES, BATCH), block TI=256.
// Plain coalesced stores of per-jseg partials (no atomics, no memset):
//   ws[(jseg*3 + c) * PLANE + b*NPART + i]
__global__ __launch_bounds__(256) void lj_kernel(const float* __restrict__ q,
                                                 float* __restrict__ ws) {
    __shared__ float qsx[SEG], qsy[SEG], qsz[SEG];

    const int jseg  = blockIdx.x;
    const int itile = blockIdx.y;
    const int b     = blockIdx.z;

    const float* qb = q + (size_t)b * NPART * 3;

    if (threadIdx.x < SEG) {
        const int k = threadIdx.x;
        const int jb = (jseg * SEG + k) * 3;
        qsx[k] = qb[jb + 0];
        qsy[k] = qb[jb + 1];
        qsz[k] = qb[jb + 2];
    }
    __syncthreads();

    const int i0 = itile * ITILE + threadIdx.x;
    float qx[IPT], qy[IPT], qz[IPT];
    #pragma unroll
    for (int k = 0; k < IPT; ++k) {
        const int i = i0 + k * TI;
        qx[k] = qb[i * 3 + 0];
        qy[k] = qb[i * 3 + 1];
        qz[k] = qb[i * 3 + 2];
    }

    v2f fx[IPT], fy[IPT], fz[IPT];
    #pragma unroll
    for (int k = 0; k < IPT; ++k) { fx[k] = (v2f)0.0f; fy[k] = (v2f)0.0f; fz[k] = (v2f)0.0f; }

    // Diagonal possible iff j-range within this block's i-range (ITILE/SEG = 8)
    if ((jseg >> 3) == itile) {
        lj_inner<true >((const v2f*)qsx, (const v2f*)qsy, (const v2f*)qsz,
                        qx, qy, qz, fx, fy, fz);
    } else {
        lj_inner<false>((const v2f*)qsx, (const v2f*)qsy, (const v2f*)qsz,
                        qx, qy, qz, fx, fy, fz);
    }

    const size_t wbase = (size_t)(jseg * 3) * PLANE + (size_t)b * NPART;
    #pragma unroll
    for (int k = 0; k < IPT; ++k) {
        const int i = i0 + k * TI;
        ws[wbase + i]             = fx[k].x + fx[k].y;
        ws[wbase + PLANE + i]     = fy[k].x + fy[k].y;
        ws[wbase + 2 * PLANE + i] = fz[k].x + fz[k].y;
    }
}

// Sum 64 per-jseg partials per dp element (L2-resident, coalesced);
// fuse dq = p/m. o in [0, 24576) maps to (c, b*NPART+i).
__global__ __launch_bounds__(256) void reduce_kernel(const float* __restrict__ ws,
                                                     const float* __restrict__ p,
                                                     const float* __restrict__ m,
                                                     float* __restrict__ dq,
                                                     float* __restrict__ dp) {
    const int o  = blockIdx.x * 256 + threadIdx.x;   // 24576 threads, 96 blocks
    const int c  = o >> 13;          // / PLANE
    const int bi = o & (PLANE - 1);  // b*NPART + i

    float s0 = 0.0f, s1 = 0.0f, s2 = 0.0f, s3 = 0.0f;
    #pragma unroll
    for (int js = 0; js < JSEGS; js += 4) {
        s0 += ws[(size_t)((js + 0) * 3 + c) * PLANE + bi];
        s1 += ws[(size_t)((js + 1) * 3 + c) * PLANE + bi];
        s2 += ws[(size_t)((js + 2) * 3 + c) * PLANE + bi];
        s3 += ws[(size_t)((js + 3) * 3 + c) * PLANE + bi];
    }
    dp[(size_t)bi * 3 + c] = (s0 + s1) + (s2 + s3);

    // dq = p/m for flat element o (exact IEEE div, only 24576 of them)
    dq[o] = p[o] / m[o / 3];
}

extern "C" void kernel_launch(void* const* d_in, const int* in_sizes, int n_in,
                              void* d_out, int out_size, void* d_ws, size_t ws_size,
                              hipStream_t stream) {
    const float* q = (const float*)d_in[0];
    const float* p = (const float*)d_in[1];
    const float* m = (const float*)d_in[2];
    // d_in[3] = t, unused by the reference outputs

    const int n_elem = BATCH * NPART * 3;   // 24576 per output tensor
    float* dq_out = (float*)d_out;          // first output: dq
    float* dp_out = (float*)d_out + n_elem; // second output: dp
    float* ws     = (float*)d_ws;           // 64*3*8192 floats = 6.3 MB partials

    dim3 grid(JSEGS, NITILES, BATCH);
    lj_kernel<<<grid, TI, 0, stream>>>(q, ws);

    reduce_kernel<<<n_elem / 256, 256, 0, stream>>>(ws, p, m, dq_out, dp_out);
}